// Round 8
// baseline (266.893 us; speedup 1.0000x reference)
//
#include <hip/hip_runtime.h>
#include <math.h>

// SegmentGatingNetwork, MFMA path v9: producer/consumer wave specialization.
// v8 diagnosis: per-CU per-iter serial sum (MFMA 3725 + LDS 2800 + VALU 2900 cyc)
// == measured 10.2k cyc/iter — barrier-locked waves serialize the pipes.
// v9: 768-thr blocks = 8 consumer waves (pure B-load + A-ds_read + MFMA, v8 code)
// + 4 producer waves (x load + split3 + LDS write, depth-2 prefetch). Staging
// leaves the consumer critical chain and runs concurrently. alds/hlds LDS union
// (35.3 KB) -> 2 blocks/CU = 24 waves/CU (6/SIMD). setprio(1) around consumer
// MFMA clusters (T5: role-split now exists). Staged bytes + MFMA order identical
// to v8 -> bit-exact.

#define DM 1024
#define DH 256
#define NE 64

// d_ws layout (bytes)
#define W1P_OFF 0                 // 3 planes * 131072 dwords
#define W1P_STRIDE 524288         // bytes per W1 plane
#define W2P_OFF 1572864           // 3 planes * 8192 dwords
#define W2P_STRIDE 32768

#define HSTR 276                  // h LDS row stride in dwords
#define AROW 144                  // bytes per token row: 128 data + 16 pad
#define APLANE 4608               // 32 tokens * AROW
#define ABUF 13824                // 3 planes
#define SMEM_BYTES 35328          // max(2*ABUF = 27648, 32*HSTR*4 = 35328)

typedef __attribute__((ext_vector_type(8))) short bf16x8;
typedef __attribute__((ext_vector_type(4))) float f32x4;

__device__ __forceinline__ unsigned fbits(float f) { return __float_as_uint(f); }
__device__ __forceinline__ float topf(unsigned u) { return __uint_as_float(u & 0xFFFF0000u); }

// truncated 3-plane split: v == top16(h)+top16(m)+top16(l) exactly
__device__ __forceinline__ void split3(float v, unsigned& h, unsigned& m, unsigned& l) {
    h = fbits(v);
    float r1 = v - topf(h);
    m = fbits(r1);
    float r2 = r1 - topf(m);
    l = fbits(r2);
}
__device__ __forceinline__ unsigned packpair(unsigned a, unsigned b) {
    return (a >> 16) | (b & 0xFFFF0000u);
}
__device__ __forceinline__ bf16x8 as_bf(uint4 u) {
    union { uint4 a; bf16x8 b; } c; c.a = u; return c.b;
}

// stage 8 consecutive k of one token: 2 float4 -> 1 uint4 per plane (b128 writes).
// Byte layout identical to v8's stage4 pairs (k-pairs packed lo-first).
__device__ __forceinline__ void stage8s(float4 f0, float4 f1, char* wb) {
    float v[8] = {f0.x, f0.y, f0.z, f0.w, f1.x, f1.y, f1.z, f1.w};
    unsigned hb[8], mb[8], lb[8];
#pragma unroll
    for (int j = 0; j < 8; j++) split3(v[j], hb[j], mb[j], lb[j]);
    uint4 uh = {packpair(hb[0], hb[1]), packpair(hb[2], hb[3]),
                packpair(hb[4], hb[5]), packpair(hb[6], hb[7])};
    uint4 um = {packpair(mb[0], mb[1]), packpair(mb[2], mb[3]),
                packpair(mb[4], mb[5]), packpair(mb[6], mb[7])};
    uint4 ul = {packpair(lb[0], lb[1]), packpair(lb[2], lb[3]),
                packpair(lb[4], lb[5]), packpair(lb[6], lb[7])};
    *(uint4*)(wb + 0 * APLANE) = uh;
    *(uint4*)(wb + 1 * APLANE) = um;
    *(uint4*)(wb + 2 * APLANE) = ul;
}

// 8 consecutive-k floats -> three bf16x8 fragments — gate phase only
__device__ __forceinline__ void split_pack8(float4 f0, float4 f1,
                                            bf16x8& H, bf16x8& M, bf16x8& L) {
    float v[8] = {f0.x, f0.y, f0.z, f0.w, f1.x, f1.y, f1.z, f1.w};
    unsigned hb[8], mb[8], lb[8];
#pragma unroll
    for (int j = 0; j < 8; j++) split3(v[j], hb[j], mb[j], lb[j]);
    uint4 uh = {packpair(hb[0], hb[1]), packpair(hb[2], hb[3]),
                packpair(hb[4], hb[5]), packpair(hb[6], hb[7])};
    uint4 um = {packpair(mb[0], mb[1]), packpair(mb[2], mb[3]),
                packpair(mb[4], mb[5]), packpair(mb[6], mb[7])};
    uint4 ul = {packpair(lb[0], lb[1]), packpair(lb[2], lb[3]),
                packpair(lb[4], lb[5]), packpair(lb[6], lb[7])};
    H = as_bf(uh); M = as_bf(um); L = as_bf(ul);
}

// Fragment conventions (empirically verified):
//   A-frag 16x16x32: m = lane&15, k = (lane>>4)*8 + j
//   B-frag:          n = lane&15, same k mapping
//   C/D:             col(n) = lane&15, row(m) = (lane>>4)*4 + reg

// ---------------- prep: weight planes in B-fragment order, LDS-tiled gather ----------------
__global__ __launch_bounds__(256)
void prep_planes(const float* __restrict__ W1, const float* __restrict__ W2,
                 char* __restrict__ ws) {
    __shared__ float tile[512];
    unsigned* w1p = (unsigned*)(ws + W1P_OFF);
    unsigned* w2p = (unsigned*)(ws + W2P_OFF);
    const int b = blockIdx.x, t = threadIdx.x;
    const int q = t & 3, L = (t >> 2) & 63;
    const int n_loc = L & 15;
    const int k_loc = ((L >> 4) & 3) * 8 + 2 * q;
    if (b < 512) {
        const int kc = b >> 4, nt = b & 15;
#pragma unroll
        for (int i = 0; i < 2; i++) {
            const int idx = t + i * 256;
            tile[idx] = W1[(size_t)(kc * 32 + (idx >> 4)) * DH + nt * 16 + (idx & 15)];
        }
        __syncthreads();
        const float v0 = tile[k_loc * 16 + n_loc];
        const float v1 = tile[(k_loc + 1) * 16 + n_loc];
        unsigned h0, m0, l0, h1, m1, l1;
        split3(v0, h0, m0, l0);
        split3(v1, h1, m1, l1);
        const int gt = b * 256 + t;
        w1p[0 * 131072 + gt] = packpair(h0, h1);
        w1p[1 * 131072 + gt] = packpair(m0, m1);
        w1p[2 * 131072 + gt] = packpair(l0, l1);
    } else {
        const int b2 = b - 512;
        const int kc = b2 >> 2, nt = b2 & 3;
#pragma unroll
        for (int i = 0; i < 2; i++) {
            const int idx = t + i * 256;
            tile[idx] = W2[(kc * 32 + (idx >> 4)) * NE + nt * 16 + (idx & 15)];
        }
        __syncthreads();
        const float v0 = tile[k_loc * 16 + n_loc];
        const float v1 = tile[(k_loc + 1) * 16 + n_loc];
        unsigned h0, m0, l0, h1, m1, l1;
        split3(v0, h0, m0, l0);
        split3(v1, h1, m1, l1);
        const int g2 = b2 * 256 + t;
        w2p[0 * 8192 + g2] = packpair(h0, h1);
        w2p[1 * 8192 + g2] = packpair(m0, m1);
        w2p[2 * 8192 + g2] = packpair(l0, l1);
    }
}

// ---------------- fused: h = tanh(x@W1+b1) ; logits = h@W2+b2 ; top-2 softmax ----------------
// 32 tokens/block, 768 threads = 12 waves: waves 0-7 consumers (hid [w*32,w*32+32)),
// waves 8-11 producers (stage A-planes, depth-2 x prefetch). BK=64, 16 iterations,
// double-buffered A in LDS (union'd with the h hand-off buffer).
__global__ __launch_bounds__(768, 6)
void fused_gating(const float* __restrict__ x, const char* __restrict__ w1p,
                  const float* __restrict__ b1, const char* __restrict__ w2p,
                  const float* __restrict__ b2, float* __restrict__ gates,
                  float* __restrict__ logits_out) {
    __shared__ __align__(16) char smem[SMEM_BYTES];   // alds (27648) ∪ hlds (35328)
    char* alds = smem;
    float* hlds = (float*)smem;

    const int tid  = threadIdx.x;
    const int lane = tid & 63;
    const int wave = tid >> 6;
    const bool producer = (wave >= 8);
    const int m15 = lane & 15;
    const int lq  = lane >> 4;
    const int t0 = blockIdx.x * 32;

    // ---- producer state ----
    const float* xs = nullptr;
    int swoff = 0;
    float4 xc0, xc1;
    if (producer) {
        const int pt = tid - 512;         // 0..255
        const int stok = pt >> 3;         // 32 tokens
        const int seg  = pt & 7;          // 8 segments of 8 k
        xs = x + (size_t)(t0 + stok) * DM + seg * 8;
        swoff = stok * AROW + seg * 16;
        // prologue: stage iter0 (k 0..63) into buf0; prefetch x(1)
        stage8s(*(const float4*)(xs), *(const float4*)(xs + 4), alds + swoff);
        xc0 = *(const float4*)(xs + 64);
        xc1 = *(const float4*)(xs + 68);
    }

    // ---- consumer state ----
    const char* bbase = w1p + (size_t)(wave * 2) * 1024 + lane * 16;  // waves 0-7 only
    f32x4 acc[2][2];
#pragma unroll
    for (int ms = 0; ms < 2; ms++)
#pragma unroll
        for (int nt = 0; nt < 2; nt++) acc[ms][nt] = (f32x4){0.f, 0.f, 0.f, 0.f};

    __syncthreads();

#pragma unroll 2
    for (int t = 0; t < 16; t++) {
        if (producer) {
            // x prefetch for iter t+2 (invariant: xc = x(t+1); wrap in-bounds, unused)
            const int kn = (t + 2) & 15;
            float4 xn0 = *(const float4*)(xs + kn * 64);
            float4 xn1 = *(const float4*)(xs + kn * 64 + 4);
            if (t < 15)
                stage8s(xc0, xc1, alds + ((t + 1) & 1) * ABUF + swoff);
            xc0 = xn0; xc1 = xn1;
        } else {
            // B loads for both sub-chunks (source order; compiler sinks under reg cap)
            const int kcA = 2 * t, kcB = 2 * t + 1;
            uint4 b0[3][2], b1f[3][2];
#pragma unroll
            for (int p = 0; p < 3; p++)
#pragma unroll
                for (int nt = 0; nt < 2; nt++) {
                    b0[p][nt]  = *(const uint4*)(bbase + p * W1P_STRIDE + kcA * 16384 + nt * 1024);
                    b1f[p][nt] = *(const uint4*)(bbase + p * W1P_STRIDE + kcB * 16384 + nt * 1024);
                }

            const char* ab = alds + (t & 1) * ABUF + m15 * AROW + lq * 16;

            // ---- sub-chunk 0 (old kc = 2t) ----
            {
                const bf16x8 a0h = *(const bf16x8*)(ab + 0 * APLANE);
                const bf16x8 a0m = *(const bf16x8*)(ab + 1 * APLANE);
                const bf16x8 a0l = *(const bf16x8*)(ab + 2 * APLANE);
                const bf16x8 a1h = *(const bf16x8*)(ab + 0 * APLANE + 16 * AROW);
                const bf16x8 a1m = *(const bf16x8*)(ab + 1 * APLANE + 16 * AROW);
                const bf16x8 a1l = *(const bf16x8*)(ab + 2 * APLANE + 16 * AROW);
                __builtin_amdgcn_s_setprio(1);
#pragma unroll
                for (int nt = 0; nt < 2; nt++) {
                    const bf16x8 bh = as_bf(b0[0][nt]);
                    const bf16x8 bm = as_bf(b0[1][nt]);
                    const bf16x8 bl = as_bf(b0[2][nt]);
                    f32x4 a0 = acc[0][nt];
                    a0 = __builtin_amdgcn_mfma_f32_16x16x32_bf16(a0h, bh, a0, 0, 0, 0);
                    a0 = __builtin_amdgcn_mfma_f32_16x16x32_bf16(a0h, bm, a0, 0, 0, 0);
                    a0 = __builtin_amdgcn_mfma_f32_16x16x32_bf16(a0m, bh, a0, 0, 0, 0);
                    a0 = __builtin_amdgcn_mfma_f32_16x16x32_bf16(a0h, bl, a0, 0, 0, 0);
                    a0 = __builtin_amdgcn_mfma_f32_16x16x32_bf16(a0l, bh, a0, 0, 0, 0);
                    a0 = __builtin_amdgcn_mfma_f32_16x16x32_bf16(a0m, bm, a0, 0, 0, 0);
                    acc[0][nt] = a0;
                    f32x4 a1 = acc[1][nt];
                    a1 = __builtin_amdgcn_mfma_f32_16x16x32_bf16(a1h, bh, a1, 0, 0, 0);
                    a1 = __builtin_amdgcn_mfma_f32_16x16x32_bf16(a1h, bm, a1, 0, 0, 0);
                    a1 = __builtin_amdgcn_mfma_f32_16x16x32_bf16(a1m, bh, a1, 0, 0, 0);
                    a1 = __builtin_amdgcn_mfma_f32_16x16x32_bf16(a1h, bl, a1, 0, 0, 0);
                    a1 = __builtin_amdgcn_mfma_f32_16x16x32_bf16(a1l, bh, a1, 0, 0, 0);
                    a1 = __builtin_amdgcn_mfma_f32_16x16x32_bf16(a1m, bm, a1, 0, 0, 0);
                    acc[1][nt] = a1;
                }
                __builtin_amdgcn_s_setprio(0);
            }
            // ---- sub-chunk 1 (old kc = 2t+1): +64 B within the row ----
            {
                const bf16x8 a0h = *(const bf16x8*)(ab + 0 * APLANE + 64);
                const bf16x8 a0m = *(const bf16x8*)(ab + 1 * APLANE + 64);
                const bf16x8 a0l = *(const bf16x8*)(ab + 2 * APLANE + 64);
                const bf16x8 a1h = *(const bf16x8*)(ab + 0 * APLANE + 16 * AROW + 64);
                const bf16x8 a1m = *(const bf16x8*)(ab + 1 * APLANE + 16 * AROW + 64);
                const bf16x8 a1l = *(const bf16x8*)(ab + 2 * APLANE + 16 * AROW + 64);
                __builtin_amdgcn_s_setprio(1);
#pragma unroll
                for (int nt = 0; nt < 2; nt++) {
                    const bf16x8 bh = as_bf(b1f[0][nt]);
                    const bf16x8 bm = as_bf(b1f[1][nt]);
                    const bf16x8 bl = as_bf(b1f[2][nt]);
                    f32x4 a0 = acc[0][nt];
                    a0 = __builtin_amdgcn_mfma_f32_16x16x32_bf16(a0h, bh, a0, 0, 0, 0);
                    a0 = __builtin_amdgcn_mfma_f32_16x16x32_bf16(a0h, bm, a0, 0, 0, 0);
                    a0 = __builtin_amdgcn_mfma_f32_16x16x32_bf16(a0m, bh, a0, 0, 0, 0);
                    a0 = __builtin_amdgcn_mfma_f32_16x16x32_bf16(a0h, bl, a0, 0, 0, 0);
                    a0 = __builtin_amdgcn_mfma_f32_16x16x32_bf16(a0l, bh, a0, 0, 0, 0);
                    a0 = __builtin_amdgcn_mfma_f32_16x16x32_bf16(a0m, bm, a0, 0, 0, 0);
                    acc[0][nt] = a0;
                    f32x4 a1 = acc[1][nt];
                    a1 = __builtin_amdgcn_mfma_f32_16x16x32_bf16(a1h, bh, a1, 0, 0, 0);
                    a1 = __builtin_amdgcn_mfma_f32_16x16x32_bf16(a1h, bm, a1, 0, 0, 0);
                    a1 = __builtin_amdgcn_mfma_f32_16x16x32_bf16(a1m, bh, a1, 0, 0, 0);
                    a1 = __builtin_amdgcn_mfma_f32_16x16x32_bf16(a1h, bl, a1, 0, 0, 0);
                    a1 = __builtin_amdgcn_mfma_f32_16x16x32_bf16(a1l, bh, a1, 0, 0, 0);
                    a1 = __builtin_amdgcn_mfma_f32_16x16x32_bf16(a1m, bm, a1, 0, 0, 0);
                    acc[1][nt] = a1;
                }
                __builtin_amdgcn_s_setprio(0);
            }
        }
        __syncthreads();
    }

    // epilogue: bias + tanh -> h in LDS (consumers only; union buffer — last alds
    // read completed before the final K-loop barrier)
    if (!producer) {
#pragma unroll
        for (int nt = 0; nt < 2; nt++) {
            const int hid = wave * 32 + nt * 16 + m15;
            const float bias = b1[hid];
#pragma unroll
            for (int ms = 0; ms < 2; ms++) {
                const int tb = ms * 16 + lq * 4;
#pragma unroll
                for (int r = 0; r < 4; r++)
                    hlds[(tb + r) * HSTR + hid] = tanhf(acc[ms][nt][r] + bias);
            }
        }
    }
    __syncthreads();

    // ---- gate phase: waves 0-1, 16 tokens each, h from LDS ----
    if (wave < 2) {
        const float* hb = hlds + (wave * 16 + m15) * HSTR + lq * 8;
        const char* bt = w2p + lane * 16;

        f32x4 gacc[4];
#pragma unroll
        for (int nt = 0; nt < 4; nt++) gacc[nt] = (f32x4){0.f, 0.f, 0.f, 0.f};

#pragma unroll
        for (int kc = 0; kc < 8; kc++) {
            float4 f0 = *(const float4*)(hb + kc * 32);
            float4 f1 = *(const float4*)(hb + kc * 32 + 4);
            bf16x8 afh, afm, afl;
            split_pack8(f0, f1, afh, afm, afl);
#pragma unroll
            for (int nt = 0; nt < 4; nt++) {
                const char* tb = bt + (kc * 4 + nt) * 1024;
                bf16x8 bh = *(const bf16x8*)(tb + 0 * W2P_STRIDE);
                bf16x8 bm = *(const bf16x8*)(tb + 1 * W2P_STRIDE);
                bf16x8 bl = *(const bf16x8*)(tb + 2 * W2P_STRIDE);
                f32x4 a = gacc[nt];
                a = __builtin_amdgcn_mfma_f32_16x16x32_bf16(afh, bh, a, 0, 0, 0);
                a = __builtin_amdgcn_mfma_f32_16x16x32_bf16(afh, bm, a, 0, 0, 0);
                a = __builtin_amdgcn_mfma_f32_16x16x32_bf16(afm, bh, a, 0, 0, 0);
                a = __builtin_amdgcn_mfma_f32_16x16x32_bf16(afh, bl, a, 0, 0, 0);
                a = __builtin_amdgcn_mfma_f32_16x16x32_bf16(afl, bh, a, 0, 0, 0);
                a = __builtin_amdgcn_mfma_f32_16x16x32_bf16(afm, bm, a, 0, 0, 0);
                gacc[nt] = a;
            }
        }

        float b2v[4];
#pragma unroll
        for (int nt = 0; nt < 4; nt++) b2v[nt] = b2[nt * 16 + m15];

        // per r: lane holds 4 experts of token t0 + wave*16 + lq*4 + r
#pragma unroll
        for (int r = 0; r < 4; r++) {
            float v[4]; int e[4];
#pragma unroll
            for (int nt = 0; nt < 4; nt++) { v[nt] = gacc[nt][r] + b2v[nt]; e[nt] = nt * 16 + m15; }

            float a1 = v[0], a2 = v[1]; int j1 = e[0], j2 = e[1];
            if (v[1] > v[0]) { a1 = v[1]; j1 = e[1]; a2 = v[0]; j2 = e[0]; }
#pragma unroll
            for (int tt = 2; tt < 4; tt++) {
                if (v[tt] > a1) { a2 = a1; j2 = j1; a1 = v[tt]; j1 = e[tt]; }
                else if (v[tt] > a2) { a2 = v[tt]; j2 = e[tt]; }
            }
#pragma unroll
            for (int off = 1; off < 16; off <<= 1) {
                float ob1 = __shfl_xor(a1, off, 64); int oj1 = __shfl_xor(j1, off, 64);
                float ob2 = __shfl_xor(a2, off, 64); int oj2 = __shfl_xor(j2, off, 64);
                bool bw = (ob1 > a1) || (ob1 == a1 && oj1 < j1);
                float w1v = bw ? ob1 : a1; int w1i = bw ? oj1 : j1;
                float lv = bw ? a1 : ob1;  int li  = bw ? j1 : oj1;   // loser of top duel
                float rv = bw ? ob2 : a2;  int ri  = bw ? oj2 : j2;   // winner side's runner-up
                bool cw = (lv > rv) || (lv == rv && li < ri);
                a1 = w1v; j1 = w1i;
                a2 = cw ? lv : rv; j2 = cw ? li : ri;
            }
            float ex = __expf(a2 - a1);            // a2 <= a1: stable
            float inv = 1.f / (1.f + ex);
            float g1 = inv, g2 = ex * inv;

            const size_t row = (size_t)(t0 + wave * 16 + lq * 4 + r) * NE;
#pragma unroll
            for (int nt = 0; nt < 4; nt++) {
                float gv = (e[nt] == j1) ? g1 : ((e[nt] == j2) ? g2 : 0.f);
                gates[row + e[nt]] = gv;
                logits_out[row + e[nt]] = v[nt];
            }
        }
    }
}

extern "C" void kernel_launch(void* const* d_in, const int* in_sizes, int n_in,
                              void* d_out, int out_size, void* d_ws, size_t ws_size,
                              hipStream_t stream) {
    const float* x  = (const float*)d_in[0];
    const float* W1 = (const float*)d_in[1];
    const float* b1 = (const float*)d_in[2];
    const float* W2 = (const float*)d_in[3];
    const float* b2 = (const float*)d_in[4];

    const int T = in_sizes[0] / DM;   // 16384
    char* ws = (char*)d_ws;
    float* gates  = (float*)d_out;
    float* logits = (float*)d_out + (size_t)T * NE;

    prep_planes<<<512 + 32, 256, 0, stream>>>(W1, W2, ws);
    fused_gating<<<T / 32, 768, 0, stream>>>(x, ws + W1P_OFF, b1, ws + W2P_OFF, b2,
                                             gates, logits);
}

// Round 9
// 145.667 us; speedup vs baseline: 1.8322x; 1.8322x over previous
//
#include <hip/hip_runtime.h>
#include <math.h>

// SegmentGatingNetwork, MFMA path v10: 64-token blocks (grid=256) to halve the
// dominant wall — B-fragment L2 traffic (∝ block count: 512x1.5MB -> 256x1.5MB).
// v9's wave specialization spilled (VGPR cap 84 vs ~100 live -> 344MB scratch);
// reverted to homogeneous 8-wave structure. Wave = 64 tok x 32 hid (ms=4,nt=2,
// 48 MFMA/kc, 8 indep acc chains for ILP at 2 waves/SIMD). BK=32, staging
// reordered BEFORE the MFMA cluster (independent -> compiler overlaps pipes).
// No vmem carried across barriers. Math identical to v5/v8 (bit-exact).

#define DM 1024
#define DH 256
#define NE 64

// d_ws layout (bytes)
#define W1P_OFF 0                 // 3 planes * 131072 dwords
#define W1P_STRIDE 524288         // bytes per W1 plane
#define W2P_OFF 1572864           // 3 planes * 8192 dwords
#define W2P_STRIDE 32768

#define HSTR 276                  // h LDS row stride in dwords
#define AROW 80                   // bytes per token row: 64 data + 16 pad
#define APLANE 5120               // 64 tokens * AROW
#define ABUF 15360                // 3 planes
#define SMEM_BYTES 70656          // max(2*ABUF=30720, 64*HSTR*4=70656)

typedef __attribute__((ext_vector_type(8))) short bf16x8;
typedef __attribute__((ext_vector_type(4))) float f32x4;

__device__ __forceinline__ unsigned fbits(float f) { return __float_as_uint(f); }
__device__ __forceinline__ float topf(unsigned u) { return __uint_as_float(u & 0xFFFF0000u); }

// truncated 3-plane split: v == top16(h)+top16(m)+top16(l) exactly
__device__ __forceinline__ void split3(float v, unsigned& h, unsigned& m, unsigned& l) {
    h = fbits(v);
    float r1 = v - topf(h);
    m = fbits(r1);
    float r2 = r1 - topf(m);
    l = fbits(r2);
}
__device__ __forceinline__ unsigned packpair(unsigned a, unsigned b) {
    return (a >> 16) | (b & 0xFFFF0000u);
}
__device__ __forceinline__ bf16x8 as_bf(uint4 u) {
    union { uint4 a; bf16x8 b; } c; c.a = u; return c.b;
}

// stage 4 consecutive k of one token: float4 -> 2 packed dwords per plane
__device__ __forceinline__ void stage4(float4 f, char* wb) {
    unsigned h[4], m[4], l[4];
    split3(f.x, h[0], m[0], l[0]);
    split3(f.y, h[1], m[1], l[1]);
    split3(f.z, h[2], m[2], l[2]);
    split3(f.w, h[3], m[3], l[3]);
    uint2 dh = {packpair(h[0], h[1]), packpair(h[2], h[3])};
    uint2 dm = {packpair(m[0], m[1]), packpair(m[2], m[3])};
    uint2 dl = {packpair(l[0], l[1]), packpair(l[2], l[3])};
    *(uint2*)(wb + 0 * APLANE) = dh;
    *(uint2*)(wb + 1 * APLANE) = dm;
    *(uint2*)(wb + 2 * APLANE) = dl;
}

// 8 consecutive-k floats -> three bf16x8 fragments — gate phase only
__device__ __forceinline__ void split_pack8(float4 f0, float4 f1,
                                            bf16x8& H, bf16x8& M, bf16x8& L) {
    float v[8] = {f0.x, f0.y, f0.z, f0.w, f1.x, f1.y, f1.z, f1.w};
    unsigned hb[8], mb[8], lb[8];
#pragma unroll
    for (int j = 0; j < 8; j++) split3(v[j], hb[j], mb[j], lb[j]);
    uint4 uh = {packpair(hb[0], hb[1]), packpair(hb[2], hb[3]),
                packpair(hb[4], hb[5]), packpair(hb[6], hb[7])};
    uint4 um = {packpair(mb[0], mb[1]), packpair(mb[2], mb[3]),
                packpair(mb[4], mb[5]), packpair(mb[6], mb[7])};
    uint4 ul = {packpair(lb[0], lb[1]), packpair(lb[2], lb[3]),
                packpair(lb[4], lb[5]), packpair(lb[6], lb[7])};
    H = as_bf(uh); M = as_bf(um); L = as_bf(ul);
}

// Fragment conventions (empirically verified):
//   A-frag 16x16x32: m = lane&15, k = (lane>>4)*8 + j
//   B-frag:          n = lane&15, same k mapping
//   C/D:             col(n) = lane&15, row(m) = (lane>>4)*4 + reg

// ---------------- prep: weight planes in B-fragment order, LDS-tiled gather ----------------
__global__ __launch_bounds__(256)
void prep_planes(const float* __restrict__ W1, const float* __restrict__ W2,
                 char* __restrict__ ws) {
    __shared__ float tile[512];
    unsigned* w1p = (unsigned*)(ws + W1P_OFF);
    unsigned* w2p = (unsigned*)(ws + W2P_OFF);
    const int b = blockIdx.x, t = threadIdx.x;
    const int q = t & 3, L = (t >> 2) & 63;
    const int n_loc = L & 15;
    const int k_loc = ((L >> 4) & 3) * 8 + 2 * q;
    if (b < 512) {
        const int kc = b >> 4, nt = b & 15;
#pragma unroll
        for (int i = 0; i < 2; i++) {
            const int idx = t + i * 256;
            tile[idx] = W1[(size_t)(kc * 32 + (idx >> 4)) * DH + nt * 16 + (idx & 15)];
        }
        __syncthreads();
        const float v0 = tile[k_loc * 16 + n_loc];
        const float v1 = tile[(k_loc + 1) * 16 + n_loc];
        unsigned h0, m0, l0, h1, m1, l1;
        split3(v0, h0, m0, l0);
        split3(v1, h1, m1, l1);
        const int gt = b * 256 + t;
        w1p[0 * 131072 + gt] = packpair(h0, h1);
        w1p[1 * 131072 + gt] = packpair(m0, m1);
        w1p[2 * 131072 + gt] = packpair(l0, l1);
    } else {
        const int b2 = b - 512;
        const int kc = b2 >> 2, nt = b2 & 3;
#pragma unroll
        for (int i = 0; i < 2; i++) {
            const int idx = t + i * 256;
            tile[idx] = W2[(kc * 32 + (idx >> 4)) * NE + nt * 16 + (idx & 15)];
        }
        __syncthreads();
        const float v0 = tile[k_loc * 16 + n_loc];
        const float v1 = tile[(k_loc + 1) * 16 + n_loc];
        unsigned h0, m0, l0, h1, m1, l1;
        split3(v0, h0, m0, l0);
        split3(v1, h1, m1, l1);
        const int g2 = b2 * 256 + t;
        w2p[0 * 8192 + g2] = packpair(h0, h1);
        w2p[1 * 8192 + g2] = packpair(m0, m1);
        w2p[2 * 8192 + g2] = packpair(l0, l1);
    }
}

// ---------------- fused: h = tanh(x@W1+b1) ; logits = h@W2+b2 ; top-2 softmax ----------------
// 64 tokens/block, 512 threads = 8 waves, wave w covers ALL 64 tokens x hid
// [w*32, w*32+32) (ms=4, nt=2). BK=32, 32 iterations, A staged in LDS (dbuf),
// B loaded in-iteration from L2 planes. Epilogue: h -> LDS, waves 0-3 gate.
__global__ __launch_bounds__(512, 2)
void fused_gating(const float* __restrict__ x, const char* __restrict__ w1p,
                  const float* __restrict__ b1, const char* __restrict__ w2p,
                  const float* __restrict__ b2, float* __restrict__ gates,
                  float* __restrict__ logits_out) {
    __shared__ __align__(16) char smem[SMEM_BYTES];   // alds (30720) ∪ hlds (70656)
    char* alds = smem;
    float* hlds = (float*)smem;

    const int tid  = threadIdx.x;
    const int lane = tid & 63;
    const int wave = tid >> 6;        // hid slice [wave*32, wave*32+32)
    const int m15 = lane & 15;
    const int lq  = lane >> 4;
    const int t0 = blockIdx.x * 64;

    // staging role: thread -> (token stok, 4-k segment seg); 512 thr = 64 tok x 8 segs
    const int stok = tid >> 3;
    const int seg  = tid & 7;
    const float* xs = x + (size_t)(t0 + stok) * DM + seg * 4;
    const int swoff = stok * AROW + seg * 8;

    // B frags: nt_global = wave*2 + nt (16 nt covered exactly once per block)
    const char* bbase = w1p + (size_t)(wave * 2) * 1024 + lane * 16;

    f32x4 acc[4][2];
#pragma unroll
    for (int ms = 0; ms < 4; ms++)
#pragma unroll
        for (int nt = 0; nt < 2; nt++) acc[ms][nt] = (f32x4){0.f, 0.f, 0.f, 0.f};

    // prologue: stage iter0 into buf0; x(1),x(2) into reg slots
    stage4(*(const float4*)(xs), alds + swoff);
    float4 xc  = *(const float4*)(xs + 32);
    float4 xc2 = *(const float4*)(xs + 64);
    __syncthreads();

#pragma unroll 2
    for (int kc = 0; kc < 32; kc++) {
        // B loads for THIS kc issued first; consumed ~after staging+A-reads (~300+ cyc)
        uint4 bc[3][2];
#pragma unroll
        for (int p = 0; p < 3; p++)
#pragma unroll
            for (int nt = 0; nt < 2; nt++)
                bc[p][nt] = *(const uint4*)(bbase + p * W1P_STRIDE + kc * 16384 + nt * 1024);
        // x prefetch for iter kc+3 (invariant: xc = kc+1, xc2 = kc+2)
        float4 xn = *(const float4*)(xs + ((kc + 3) & 31) * 32);

        // stage kc+1 BEFORE the MFMA cluster (independent of it; buffer safe:
        // buf[(kc+1)&1] was last read in iter kc-1, fenced by that barrier)
        if (kc < 31)
            stage4(xc, alds + ((kc + 1) & 1) * ABUF + swoff);
        xc = xc2; xc2 = xn;

        // A-frags from LDS current buffer: 4 ms x 3 planes
        const char* ab = alds + (kc & 1) * ABUF + m15 * AROW + lq * 16;
        bf16x8 af[4][3];
#pragma unroll
        for (int ms = 0; ms < 4; ms++)
#pragma unroll
            for (int p = 0; p < 3; p++)
                af[ms][p] = *(const bf16x8*)(ab + p * APLANE + ms * (16 * AROW));

#pragma unroll
        for (int ms = 0; ms < 4; ms++)
#pragma unroll
            for (int nt = 0; nt < 2; nt++) {
                const bf16x8 ah = af[ms][0];
                const bf16x8 am = af[ms][1];
                const bf16x8 al = af[ms][2];
                const bf16x8 bh = as_bf(bc[0][nt]);
                const bf16x8 bm = as_bf(bc[1][nt]);
                const bf16x8 bl = as_bf(bc[2][nt]);
                f32x4 a = acc[ms][nt];
                a = __builtin_amdgcn_mfma_f32_16x16x32_bf16(ah, bh, a, 0, 0, 0);
                a = __builtin_amdgcn_mfma_f32_16x16x32_bf16(ah, bm, a, 0, 0, 0);
                a = __builtin_amdgcn_mfma_f32_16x16x32_bf16(am, bh, a, 0, 0, 0);
                a = __builtin_amdgcn_mfma_f32_16x16x32_bf16(ah, bl, a, 0, 0, 0);
                a = __builtin_amdgcn_mfma_f32_16x16x32_bf16(al, bh, a, 0, 0, 0);
                a = __builtin_amdgcn_mfma_f32_16x16x32_bf16(am, bm, a, 0, 0, 0);
                acc[ms][nt] = a;
            }

        __syncthreads();
    }

    // epilogue: bias + tanh -> h in LDS (C/D layout: col = m15, row = lq*4 + r)
#pragma unroll
    for (int nt = 0; nt < 2; nt++) {
        const int hid = wave * 32 + nt * 16 + m15;
        const float bias = b1[hid];
#pragma unroll
        for (int ms = 0; ms < 4; ms++) {
            const int tb = ms * 16 + lq * 4;
#pragma unroll
            for (int r = 0; r < 4; r++)
                hlds[(tb + r) * HSTR + hid] = tanhf(acc[ms][nt][r] + bias);
        }
    }
    __syncthreads();

    // ---- gate phase: waves 0-3, 16 tokens each, h from LDS ----
    if (wave < 4) {
        const float* hb = hlds + (wave * 16 + m15) * HSTR + lq * 8;
        const char* bt = w2p + lane * 16;

        f32x4 gacc[4];
#pragma unroll
        for (int nt = 0; nt < 4; nt++) gacc[nt] = (f32x4){0.f, 0.f, 0.f, 0.f};

#pragma unroll
        for (int kc = 0; kc < 8; kc++) {
            float4 f0 = *(const float4*)(hb + kc * 32);
            float4 f1 = *(const float4*)(hb + kc * 32 + 4);
            bf16x8 afh, afm, afl;
            split_pack8(f0, f1, afh, afm, afl);
#pragma unroll
            for (int nt = 0; nt < 4; nt++) {
                const char* tb = bt + (kc * 4 + nt) * 1024;
                bf16x8 bh = *(const bf16x8*)(tb + 0 * W2P_STRIDE);
                bf16x8 bm = *(const bf16x8*)(tb + 1 * W2P_STRIDE);
                bf16x8 bl = *(const bf16x8*)(tb + 2 * W2P_STRIDE);
                f32x4 a = gacc[nt];
                a = __builtin_amdgcn_mfma_f32_16x16x32_bf16(afh, bh, a, 0, 0, 0);
                a = __builtin_amdgcn_mfma_f32_16x16x32_bf16(afh, bm, a, 0, 0, 0);
                a = __builtin_amdgcn_mfma_f32_16x16x32_bf16(afm, bh, a, 0, 0, 0);
                a = __builtin_amdgcn_mfma_f32_16x16x32_bf16(afh, bl, a, 0, 0, 0);
                a = __builtin_amdgcn_mfma_f32_16x16x32_bf16(afl, bh, a, 0, 0, 0);
                a = __builtin_amdgcn_mfma_f32_16x16x32_bf16(afm, bm, a, 0, 0, 0);
                gacc[nt] = a;
            }
        }

        float b2v[4];
#pragma unroll
        for (int nt = 0; nt < 4; nt++) b2v[nt] = b2[nt * 16 + m15];

        // per r: lane holds 4 experts of token t0 + wave*16 + lq*4 + r
#pragma unroll
        for (int r = 0; r < 4; r++) {
            float v[4]; int e[4];
#pragma unroll
            for (int nt = 0; nt < 4; nt++) { v[nt] = gacc[nt][r] + b2v[nt]; e[nt] = nt * 16 + m15; }

            float a1 = v[0], a2 = v[1]; int j1 = e[0], j2 = e[1];
            if (v[1] > v[0]) { a1 = v[1]; j1 = e[1]; a2 = v[0]; j2 = e[0]; }
#pragma unroll
            for (int tt = 2; tt < 4; tt++) {
                if (v[tt] > a1) { a2 = a1; j2 = j1; a1 = v[tt]; j1 = e[tt]; }
                else if (v[tt] > a2) { a2 = v[tt]; j2 = e[tt]; }
            }
#pragma unroll
            for (int off = 1; off < 16; off <<= 1) {
                float ob1 = __shfl_xor(a1, off, 64); int oj1 = __shfl_xor(j1, off, 64);
                float ob2 = __shfl_xor(a2, off, 64); int oj2 = __shfl_xor(j2, off, 64);
                bool bw = (ob1 > a1) || (ob1 == a1 && oj1 < j1);
                float w1v = bw ? ob1 : a1; int w1i = bw ? oj1 : j1;
                float lv = bw ? a1 : ob1;  int li  = bw ? j1 : oj1;   // loser of top duel
                float rv = bw ? ob2 : a2;  int ri  = bw ? oj2 : j2;   // winner side's runner-up
                bool cw = (lv > rv) || (lv == rv && li < ri);
                a1 = w1v; j1 = w1i;
                a2 = cw ? lv : rv; j2 = cw ? li : ri;
            }
            float ex = __expf(a2 - a1);            // a2 <= a1: stable
            float inv = 1.f / (1.f + ex);
            float g1 = inv, g2 = ex * inv;

            const size_t row = (size_t)(t0 + wave * 16 + lq * 4 + r) * NE;
#pragma unroll
            for (int nt = 0; nt < 4; nt++) {
                float gv = (e[nt] == j1) ? g1 : ((e[nt] == j2) ? g2 : 0.f);
                gates[row + e[nt]] = gv;
                logits_out[row + e[nt]] = v[nt];
            }
        }
    }
}

extern "C" void kernel_launch(void* const* d_in, const int* in_sizes, int n_in,
                              void* d_out, int out_size, void* d_ws, size_t ws_size,
                              hipStream_t stream) {
    const float* x  = (const float*)d_in[0];
    const float* W1 = (const float*)d_in[1];
    const float* b1 = (const float*)d_in[2];
    const float* W2 = (const float*)d_in[3];
    const float* b2 = (const float*)d_in[4];

    const int T = in_sizes[0] / DM;   // 16384
    char* ws = (char*)d_ws;
    float* gates  = (float*)d_out;
    float* logits = (float*)d_out + (size_t)T * NE;

    prep_planes<<<512 + 32, 256, 0, stream>>>(W1, W2, ws);
    fused_gating<<<T / 64, 512, 0, stream>>>(x, ws + W1P_OFF, b1, ws + W2P_OFF, b2,
                                             gates, logits);
}

// Round 10
// 145.379 us; speedup vs baseline: 1.8358x; 1.0020x over previous
//
#include <hip/hip_runtime.h>
#include <math.h>

// SegmentGatingNetwork, MFMA path v11: producer/consumer waves, register-budget fixed.
// Diagnosis: v8 (16 waves/CU, 2x B-traffic, 16 barriers) == v10 (8 waves/CU, 1x,
// 32 barriers) == ~67us -> pipes run SERIALLY (barrier phase-lock); sum-of-pipes
// matches measured wall. v9 tested specialization but spilled (VGPR cap 84 < ~110
// live -> 344MB scratch). v11: same concept, __launch_bounds__(768,2) (cap 256),
// consumer geometry = v10 (64tok x 32hid/wave, acc[4][2]). 8 consumer waves
// {B-load, A-ds_read, MFMA} run concurrently with 4 producer waves {x-load,
// split3, LDS-write}. Staged bytes + MFMA order identical to v10 -> bit-exact.

#define DM 1024
#define DH 256
#define NE 64

// d_ws layout (bytes)
#define W1P_OFF 0                 // 3 planes * 131072 dwords
#define W1P_STRIDE 524288         // bytes per W1 plane
#define W2P_OFF 1572864           // 3 planes * 8192 dwords
#define W2P_STRIDE 32768

#define HSTR 276                  // h LDS row stride in dwords
#define AROW 80                   // bytes per token row: 64 data + 16 pad
#define APLANE 5120               // 64 tokens * AROW
#define ABUF 15360                // 3 planes
#define SMEM_BYTES 70656          // max(2*ABUF=30720, 64*HSTR*4=70656)

typedef __attribute__((ext_vector_type(8))) short bf16x8;
typedef __attribute__((ext_vector_type(4))) float f32x4;

__device__ __forceinline__ unsigned fbits(float f) { return __float_as_uint(f); }
__device__ __forceinline__ float topf(unsigned u) { return __uint_as_float(u & 0xFFFF0000u); }

// truncated 3-plane split: v == top16(h)+top16(m)+top16(l) exactly
__device__ __forceinline__ void split3(float v, unsigned& h, unsigned& m, unsigned& l) {
    h = fbits(v);
    float r1 = v - topf(h);
    m = fbits(r1);
    float r2 = r1 - topf(m);
    l = fbits(r2);
}
__device__ __forceinline__ unsigned packpair(unsigned a, unsigned b) {
    return (a >> 16) | (b & 0xFFFF0000u);
}
__device__ __forceinline__ bf16x8 as_bf(uint4 u) {
    union { uint4 a; bf16x8 b; } c; c.a = u; return c.b;
}

// stage 8 consecutive k of one token: 2 float4 -> 1 uint4 per plane (b128 writes)
__device__ __forceinline__ void stage8s(float4 f0, float4 f1, char* wb) {
    float v[8] = {f0.x, f0.y, f0.z, f0.w, f1.x, f1.y, f1.z, f1.w};
    unsigned hb[8], mb[8], lb[8];
#pragma unroll
    for (int j = 0; j < 8; j++) split3(v[j], hb[j], mb[j], lb[j]);
    uint4 uh = {packpair(hb[0], hb[1]), packpair(hb[2], hb[3]),
                packpair(hb[4], hb[5]), packpair(hb[6], hb[7])};
    uint4 um = {packpair(mb[0], mb[1]), packpair(mb[2], mb[3]),
                packpair(mb[4], mb[5]), packpair(mb[6], mb[7])};
    uint4 ul = {packpair(lb[0], lb[1]), packpair(lb[2], lb[3]),
                packpair(lb[4], lb[5]), packpair(lb[6], lb[7])};
    *(uint4*)(wb + 0 * APLANE) = uh;
    *(uint4*)(wb + 1 * APLANE) = um;
    *(uint4*)(wb + 2 * APLANE) = ul;
}

// 8 consecutive-k floats -> three bf16x8 fragments — gate phase only
__device__ __forceinline__ void split_pack8(float4 f0, float4 f1,
                                            bf16x8& H, bf16x8& M, bf16x8& L) {
    float v[8] = {f0.x, f0.y, f0.z, f0.w, f1.x, f1.y, f1.z, f1.w};
    unsigned hb[8], mb[8], lb[8];
#pragma unroll
    for (int j = 0; j < 8; j++) split3(v[j], hb[j], mb[j], lb[j]);
    uint4 uh = {packpair(hb[0], hb[1]), packpair(hb[2], hb[3]),
                packpair(hb[4], hb[5]), packpair(hb[6], hb[7])};
    uint4 um = {packpair(mb[0], mb[1]), packpair(mb[2], mb[3]),
                packpair(mb[4], mb[5]), packpair(mb[6], mb[7])};
    uint4 ul = {packpair(lb[0], lb[1]), packpair(lb[2], lb[3]),
                packpair(lb[4], lb[5]), packpair(lb[6], lb[7])};
    H = as_bf(uh); M = as_bf(um); L = as_bf(ul);
}

// Fragment conventions (empirically verified):
//   A-frag 16x16x32: m = lane&15, k = (lane>>4)*8 + j
//   B-frag:          n = lane&15, same k mapping
//   C/D:             col(n) = lane&15, row(m) = (lane>>4)*4 + reg

// ---------------- prep: weight planes in B-fragment order, LDS-tiled gather ----------------
__global__ __launch_bounds__(256)
void prep_planes(const float* __restrict__ W1, const float* __restrict__ W2,
                 char* __restrict__ ws) {
    __shared__ float tile[512];
    unsigned* w1p = (unsigned*)(ws + W1P_OFF);
    unsigned* w2p = (unsigned*)(ws + W2P_OFF);
    const int b = blockIdx.x, t = threadIdx.x;
    const int q = t & 3, L = (t >> 2) & 63;
    const int n_loc = L & 15;
    const int k_loc = ((L >> 4) & 3) * 8 + 2 * q;
    if (b < 512) {
        const int kc = b >> 4, nt = b & 15;
#pragma unroll
        for (int i = 0; i < 2; i++) {
            const int idx = t + i * 256;
            tile[idx] = W1[(size_t)(kc * 32 + (idx >> 4)) * DH + nt * 16 + (idx & 15)];
        }
        __syncthreads();
        const float v0 = tile[k_loc * 16 + n_loc];
        const float v1 = tile[(k_loc + 1) * 16 + n_loc];
        unsigned h0, m0, l0, h1, m1, l1;
        split3(v0, h0, m0, l0);
        split3(v1, h1, m1, l1);
        const int gt = b * 256 + t;
        w1p[0 * 131072 + gt] = packpair(h0, h1);
        w1p[1 * 131072 + gt] = packpair(m0, m1);
        w1p[2 * 131072 + gt] = packpair(l0, l1);
    } else {
        const int b2 = b - 512;
        const int kc = b2 >> 2, nt = b2 & 3;
#pragma unroll
        for (int i = 0; i < 2; i++) {
            const int idx = t + i * 256;
            tile[idx] = W2[(kc * 32 + (idx >> 4)) * NE + nt * 16 + (idx & 15)];
        }
        __syncthreads();
        const float v0 = tile[k_loc * 16 + n_loc];
        const float v1 = tile[(k_loc + 1) * 16 + n_loc];
        unsigned h0, m0, l0, h1, m1, l1;
        split3(v0, h0, m0, l0);
        split3(v1, h1, m1, l1);
        const int g2 = b2 * 256 + t;
        w2p[0 * 8192 + g2] = packpair(h0, h1);
        w2p[1 * 8192 + g2] = packpair(m0, m1);
        w2p[2 * 8192 + g2] = packpair(l0, l1);
    }
}

// ---------------- fused: h = tanh(x@W1+b1) ; logits = h@W2+b2 ; top-2 softmax ----------------
// 64 tokens/block, 768 threads = 12 waves. Waves 0-7: consumers, wave w covers all
// 64 tokens x hid [w*32, w*32+32) (ms=4, nt=2, 48 MFMA/kc). Waves 8-11: producers,
// stage the 64x32 A-chunk (split3 -> 3 planes) one iteration ahead, depth-2 x prefetch.
__global__ __launch_bounds__(768, 2)
void fused_gating(const float* __restrict__ x, const char* __restrict__ w1p,
                  const float* __restrict__ b1, const char* __restrict__ w2p,
                  const float* __restrict__ b2, float* __restrict__ gates,
                  float* __restrict__ logits_out) {
    __shared__ __align__(16) char smem[SMEM_BYTES];   // alds (30720) ∪ hlds (70656)
    char* alds = smem;
    float* hlds = (float*)smem;

    const int tid  = threadIdx.x;
    const int lane = tid & 63;
    const int wave = tid >> 6;
    const bool producer = (wave >= 8);
    const int m15 = lane & 15;
    const int lq  = lane >> 4;
    const int t0 = blockIdx.x * 64;

    // ---- producer state: 256 threads = 64 tok x 4 segs of 8 k ----
    const float* xs = nullptr;
    int swoff = 0;
    float4 xc0, xc1, xc20, xc21;
    if (producer) {
        const int pt = tid - 512;          // 0..255
        const int stok = pt >> 2;          // 64 tokens
        const int seg  = pt & 3;           // 4 segments of 8 k
        xs = x + (size_t)(t0 + stok) * DM + seg * 8;
        swoff = stok * AROW + seg * 16;
        // prologue: stage iter0 (k 0..31); prefetch x(1), x(2)
        stage8s(*(const float4*)(xs), *(const float4*)(xs + 4), alds + swoff);
        xc0  = *(const float4*)(xs + 32);
        xc1  = *(const float4*)(xs + 36);
        xc20 = *(const float4*)(xs + 64);
        xc21 = *(const float4*)(xs + 68);
    }

    // ---- consumer state ----
    const char* bbase = w1p + (size_t)(wave * 2) * 1024 + lane * 16;  // waves 0-7 valid
    f32x4 acc[4][2];
#pragma unroll
    for (int ms = 0; ms < 4; ms++)
#pragma unroll
        for (int nt = 0; nt < 2; nt++) acc[ms][nt] = (f32x4){0.f, 0.f, 0.f, 0.f};

    __syncthreads();

    for (int kc = 0; kc < 32; kc++) {
        if (producer) {
            if (kc < 31) {
                // x prefetch for iter kc+3 (invariant: xc = kc+1, xc2 = kc+2)
                const int kn = (kc + 3) & 31;
                float4 xn0 = *(const float4*)(xs + kn * 32);
                float4 xn1 = *(const float4*)(xs + kn * 32 + 4);
                // stage kc+1 into the other buffer (xc loaded >=2 iters ago)
                stage8s(xc0, xc1, alds + ((kc + 1) & 1) * ABUF + swoff);
                xc0 = xc20; xc1 = xc21;
                xc20 = xn0; xc21 = xn1;
            }
        } else {
            // B loads for THIS kc issued first (L2; consumed after A-reads)
            uint4 bc[3][2];
#pragma unroll
            for (int p = 0; p < 3; p++)
#pragma unroll
                for (int nt = 0; nt < 2; nt++)
                    bc[p][nt] = *(const uint4*)(bbase + p * W1P_STRIDE + kc * 16384 + nt * 1024);

            // A-frags from LDS current buffer: 4 ms x 3 planes
            const char* ab = alds + (kc & 1) * ABUF + m15 * AROW + lq * 16;
            bf16x8 af[4][3];
#pragma unroll
            for (int ms = 0; ms < 4; ms++)
#pragma unroll
                for (int p = 0; p < 3; p++)
                    af[ms][p] = *(const bf16x8*)(ab + p * APLANE + ms * (16 * AROW));

            __builtin_amdgcn_s_setprio(1);
#pragma unroll
            for (int ms = 0; ms < 4; ms++)
#pragma unroll
                for (int nt = 0; nt < 2; nt++) {
                    const bf16x8 ah = af[ms][0];
                    const bf16x8 am = af[ms][1];
                    const bf16x8 al = af[ms][2];
                    const bf16x8 bh = as_bf(bc[0][nt]);
                    const bf16x8 bm = as_bf(bc[1][nt]);
                    const bf16x8 bl = as_bf(bc[2][nt]);
                    f32x4 a = acc[ms][nt];
                    a = __builtin_amdgcn_mfma_f32_16x16x32_bf16(ah, bh, a, 0, 0, 0);
                    a = __builtin_amdgcn_mfma_f32_16x16x32_bf16(ah, bm, a, 0, 0, 0);
                    a = __builtin_amdgcn_mfma_f32_16x16x32_bf16(am, bh, a, 0, 0, 0);
                    a = __builtin_amdgcn_mfma_f32_16x16x32_bf16(ah, bl, a, 0, 0, 0);
                    a = __builtin_amdgcn_mfma_f32_16x16x32_bf16(al, bh, a, 0, 0, 0);
                    a = __builtin_amdgcn_mfma_f32_16x16x32_bf16(am, bm, a, 0, 0, 0);
                    acc[ms][nt] = a;
                }
            __builtin_amdgcn_s_setprio(0);
        }
        __syncthreads();
    }

    // epilogue: bias + tanh -> h in LDS (consumers only; alds/hlds union is safe —
    // all K-loop LDS reads drained by the final loop barrier)
    if (!producer) {
#pragma unroll
        for (int nt = 0; nt < 2; nt++) {
            const int hid = wave * 32 + nt * 16 + m15;
            const float bias = b1[hid];
#pragma unroll
            for (int ms = 0; ms < 4; ms++) {
                const int tb = ms * 16 + lq * 4;
#pragma unroll
                for (int r = 0; r < 4; r++)
                    hlds[(tb + r) * HSTR + hid] = tanhf(acc[ms][nt][r] + bias);
            }
        }
    }
    __syncthreads();

    // ---- gate phase: waves 0-3, 16 tokens each, h from LDS ----
    if (wave < 4) {
        const float* hb = hlds + (wave * 16 + m15) * HSTR + lq * 8;
        const char* bt = w2p + lane * 16;

        f32x4 gacc[4];
#pragma unroll
        for (int nt = 0; nt < 4; nt++) gacc[nt] = (f32x4){0.f, 0.f, 0.f, 0.f};

#pragma unroll
        for (int kc = 0; kc < 8; kc++) {
            float4 f0 = *(const float4*)(hb + kc * 32);
            float4 f1 = *(const float4*)(hb + kc * 32 + 4);
            bf16x8 afh, afm, afl;
            split_pack8(f0, f1, afh, afm, afl);
#pragma unroll
            for (int nt = 0; nt < 4; nt++) {
                const char* tb = bt + (kc * 4 + nt) * 1024;
                bf16x8 bh = *(const bf16x8*)(tb + 0 * W2P_STRIDE);
                bf16x8 bm = *(const bf16x8*)(tb + 1 * W2P_STRIDE);
                bf16x8 bl = *(const bf16x8*)(tb + 2 * W2P_STRIDE);
                f32x4 a = gacc[nt];
                a = __builtin_amdgcn_mfma_f32_16x16x32_bf16(afh, bh, a, 0, 0, 0);
                a = __builtin_amdgcn_mfma_f32_16x16x32_bf16(afh, bm, a, 0, 0, 0);
                a = __builtin_amdgcn_mfma_f32_16x16x32_bf16(afm, bh, a, 0, 0, 0);
                a = __builtin_amdgcn_mfma_f32_16x16x32_bf16(afh, bl, a, 0, 0, 0);
                a = __builtin_amdgcn_mfma_f32_16x16x32_bf16(afl, bh, a, 0, 0, 0);
                a = __builtin_amdgcn_mfma_f32_16x16x32_bf16(afm, bm, a, 0, 0, 0);
                gacc[nt] = a;
            }
        }

        float b2v[4];
#pragma unroll
        for (int nt = 0; nt < 4; nt++) b2v[nt] = b2[nt * 16 + m15];

        // per r: lane holds 4 experts of token t0 + wave*16 + lq*4 + r
#pragma unroll
        for (int r = 0; r < 4; r++) {
            float v[4]; int e[4];
#pragma unroll
            for (int nt = 0; nt < 4; nt++) { v[nt] = gacc[nt][r] + b2v[nt]; e[nt] = nt * 16 + m15; }

            float a1 = v[0], a2 = v[1]; int j1 = e[0], j2 = e[1];
            if (v[1] > v[0]) { a1 = v[1]; j1 = e[1]; a2 = v[0]; j2 = e[0]; }
#pragma unroll
            for (int tt = 2; tt < 4; tt++) {
                if (v[tt] > a1) { a2 = a1; j2 = j1; a1 = v[tt]; j1 = e[tt]; }
                else if (v[tt] > a2) { a2 = v[tt]; j2 = e[tt]; }
            }
#pragma unroll
            for (int off = 1; off < 16; off <<= 1) {
                float ob1 = __shfl_xor(a1, off, 64); int oj1 = __shfl_xor(j1, off, 64);
                float ob2 = __shfl_xor(a2, off, 64); int oj2 = __shfl_xor(j2, off, 64);
                bool bw = (ob1 > a1) || (ob1 == a1 && oj1 < j1);
                float w1v = bw ? ob1 : a1; int w1i = bw ? oj1 : j1;
                float lv = bw ? a1 : ob1;  int li  = bw ? j1 : oj1;   // loser of top duel
                float rv = bw ? ob2 : a2;  int ri  = bw ? oj2 : j2;   // winner side's runner-up
                bool cw = (lv > rv) || (lv == rv && li < ri);
                a1 = w1v; j1 = w1i;
                a2 = cw ? lv : rv; j2 = cw ? li : ri;
            }
            float ex = __expf(a2 - a1);            // a2 <= a1: stable
            float inv = 1.f / (1.f + ex);
            float g1 = inv, g2 = ex * inv;

            const size_t row = (size_t)(t0 + wave * 16 + lq * 4 + r) * NE;
#pragma unroll
            for (int nt = 0; nt < 4; nt++) {
                float gv = (e[nt] == j1) ? g1 : ((e[nt] == j2) ? g2 : 0.f);
                gates[row + e[nt]] = gv;
                logits_out[row + e[nt]] = v[nt];
            }
        }
    }
}

extern "C" void kernel_launch(void* const* d_in, const int* in_sizes, int n_in,
                              void* d_out, int out_size, void* d_ws, size_t ws_size,
                              hipStream_t stream) {
    const float* x  = (const float*)d_in[0];
    const float* W1 = (const float*)d_in[1];
    const float* b1 = (const float*)d_in[2];
    const float* W2 = (const float*)d_in[3];
    const float* b2 = (const float*)d_in[4];

    const int T = in_sizes[0] / DM;   // 16384
    char* ws = (char*)d_ws;
    float* gates  = (float*)d_out;
    float* logits = (float*)d_out + (size_t)T * NE;

    prep_planes<<<512 + 32, 256, 0, stream>>>(W1, W2, ws);
    fused_gating<<<T / 64, 768, 0, stream>>>(x, ws + W1P_OFF, b1, ws + W2P_OFF, b2,
                                             gates, logits);
}